// Round 19
// baseline (306.367 us; speedup 1.0000x reference)
//
#include <hip/hip_runtime.h>
#include <cstddef>
#include <cstdint>

typedef __attribute__((ext_vector_type(8))) short bf16x8;
typedef __attribute__((ext_vector_type(4))) float f32x4;
typedef __attribute__((ext_vector_type(8))) unsigned short u16x8;

__device__ inline unsigned short f2bf(float f) {
    unsigned u = __builtin_bit_cast(unsigned, f);
    u += 0x7FFF + ((u >> 16) & 1);          // round-to-nearest-even
    return (unsigned short)(u >> 16);
}
__device__ inline float bfbits_lo(unsigned v) { return __builtin_bit_cast(float, v << 16); }
__device__ inline float bfbits_hi(unsigned v) { return __builtin_bit_cast(float, v & 0xffff0000u); }
__device__ inline float bf2f(unsigned short b) { return __builtin_bit_cast(float, (unsigned)b << 16); }

// fast device math (v_exp_f32 / v_rcp_f32 paths)
__device__ inline float fsigmoid(float x) { return 1.0f / (1.0f + __expf(-x)); }
__device__ inline float ftanh(float x)    { return 1.0f - 2.0f / (__expf(2.0f * x) + 1.0f); }

// XOR-swizzled byte offset into a [rows][32 bf16] LDS tile (64B rows).
__device__ inline int swzB(int row, int slot) {
    return row * 64 + ((slot ^ ((row >> 1) & 3)) << 4);
}
__device__ inline bf16x8 ldbf8(const unsigned short* p) {
    u16x8 v = *(const u16x8*)p;
    return __builtin_bit_cast(bf16x8, v);
}

// ---------------- weight prepack: P[kc][c][kk] = Bop[k=kc*32+kk][c] ----------------
__global__ __launch_bounds__(256)
void prepack_kernel(const float* __restrict__ S, unsigned short* __restrict__ P,
                    int K, int C, int trans)
{
    int idx = blockIdx.x * 256 + threadIdx.x;
    if (idx >= K * C) return;
    int kk = idx & 31;
    int c  = (idx >> 5) % C;
    int kc = idx / (32 * C);
    int k  = kc * 32 + kk;
    float v = trans ? S[(size_t)c * K + k] : S[(size_t)k * C + c];
    P[idx] = f2bf(v);
}

// ---------------- combined weight: Wc = Wm @ Wih^T, packed [kc][c:384][kk] ----------------
__global__ __launch_bounds__(256)
void wcomb_kernel(const float* __restrict__ Wm, const float* __restrict__ Wih,
                  unsigned short* __restrict__ P)
{
    int idx = blockIdx.x * 256 + threadIdx.x;   // 4*384*32 = 49152
    int kk = idx & 31;
    int c  = (idx >> 5) % 384;
    int kc = idx / (32 * 384);
    int d  = kc * 32 + kk;
    const float4* a = (const float4*)&Wm[(size_t)d * 128];
    const float4* b = (const float4*)&Wih[(size_t)c * 128];
    float s = 0.0f;
#pragma unroll 8
    for (int t = 0; t < 32; ++t) {
        float4 av = a[t], bv = b[t];
        s += av.x * bv.x + av.y * bv.y + av.z * bv.z + av.w * bv.w;
    }
    P[idx] = f2bf(s);
}

// ---------------- MFMA GEMM (input projection): h_bf = bf16(x@linW + b) ----------------
template<int KC>
__global__ __launch_bounds__(256)
void mfma_xw(const float* __restrict__ A, const unsigned short* __restrict__ P,
             const float* __restrict__ bias, unsigned short* __restrict__ Cbf, int M)
{
    __shared__ unsigned short Ab[KC * 2048];   // [kc][64 rows][32 k], swizzled per kc
    const int tid  = threadIdx.x;
    const int l    = tid & 63;
    const int w    = tid >> 6;
    const int wr   = w >> 1, wc = w & 1;
    const int row0 = blockIdx.x * 64;
    const int K    = KC * 32;

    {
        int row = tid >> 2, slot = tid & 3, kpos = slot * 8;
#pragma unroll
        for (int kc = 0; kc < KC; ++kc) {
            unsigned short u[8];
            if (row0 + row < M) {
                const float* src = &A[(size_t)(row0 + row) * K + kc * 32 + kpos];
                float4 v0 = *(const float4*)src;
                float4 v1 = *(const float4*)(src + 4);
                u[0]=f2bf(v0.x); u[1]=f2bf(v0.y); u[2]=f2bf(v0.z); u[3]=f2bf(v0.w);
                u[4]=f2bf(v1.x); u[5]=f2bf(v1.y); u[6]=f2bf(v1.z); u[7]=f2bf(v1.w);
            } else {
#pragma unroll
                for (int q = 0; q < 8; ++q) u[q] = 0;
            }
            *(u16x8*)((char*)Ab + kc * 4096 + swzB(row, slot)) = *(u16x8*)u;
        }
    }
    __syncthreads();

    f32x4 acc[2][4];
#pragma unroll
    for (int i = 0; i < 2; ++i)
#pragma unroll
        for (int j = 0; j < 4; ++j) acc[i][j] = (f32x4){0.f, 0.f, 0.f, 0.f};

#pragma unroll
    for (int kc = 0; kc < KC; ++kc) {
        bf16x8 af[2], bf[4];
#pragma unroll
        for (int rt = 0; rt < 2; ++rt)
            af[rt] = *(const bf16x8*)((const char*)Ab + kc * 4096 +
                                      swzB(wr * 32 + rt * 16 + (l & 15), l >> 4));
#pragma unroll
        for (int ct = 0; ct < 4; ++ct) {
            int c = wc * 64 + ct * 16 + (l & 15);
            bf[ct] = ldbf8(&P[(size_t)kc * 4096 + c * 32 + (l >> 4) * 8]);
        }
#pragma unroll
        for (int rt = 0; rt < 2; ++rt)
#pragma unroll
            for (int ct = 0; ct < 4; ++ct)
                acc[rt][ct] = __builtin_amdgcn_mfma_f32_16x16x32_bf16(af[rt], bf[ct], acc[rt][ct], 0, 0, 0);
    }

#pragma unroll
    for (int rt = 0; rt < 2; ++rt)
#pragma unroll
        for (int ct = 0; ct < 4; ++ct) {
            int col = wc * 64 + ct * 16 + (l & 15);
            float bv = bias ? bias[col] : 0.0f;
#pragma unroll
            for (int j = 0; j < 4; ++j) {
                int row = row0 + wr * 32 + rt * 16 + (l >> 4) * 4 + j;
                if (row < M) Cbf[(size_t)row * 128 + col] = f2bf(acc[rt][ct][j] + bv);
            }
        }
}

// ---------------- fused gather + gi/gh GEMMs + GRU ----------------
// One tile per block (grid = NT). Staging phase performs the edge-gather inline.
// NOTE: hbf (input) and houtbf (output) MUST be different buffers — other blocks
// gather arbitrary rows of hbf while this block writes its output (ping-pong).
template<int ELU, int OUTF32>
__global__ __launch_bounds__(512, 2)
void mfma_gru(const int* __restrict__ off, const int* __restrict__ ssrc,
              const unsigned short* __restrict__ hbf,
              const unsigned short* __restrict__ wcP, const unsigned short* __restrict__ whhP,
              const float* __restrict__ bih, const float* __restrict__ bhh,
              float* __restrict__ hout, unsigned short* __restrict__ houtbf, int M)
{
    __shared__ unsigned short Aa[4096];   // [kc][32 rows][32 k] swizzled, 8KB
    __shared__ unsigned short Ah[4096];
    const int tid = threadIdx.x;
    const int l   = tid & 63;
    const int g   = tid >> 6;             // wave = unit group

    const int skc = tid >> 7;             // staging kc (0..3)
    const int t3  = tid & 127;
    const int srow = t3 >> 2, sslot = t3 & 3, skpos = sslot * 8;
    const int slbyte = skc * 2048 + swzB(srow, sslot);
    const int row0 = blockIdx.x * 32;

    const int unit = g * 16 + (l & 15);
    const int kcu = unit >> 5, slotu = (unit & 31) >> 3, elemu = unit & 7;
    const float bir = bih[unit], biz = bih[128 + unit], bin = bih[256 + unit];
    const float bhr = bhh[unit], bhz = bhh[128 + unit], bhn = bhh[256 + unit];

    // B fragments in registers (block-invariant): 24 x bf16x8 = 96 VGPR
    bf16x8 BW[4][3], BU[4][3];
#pragma unroll
    for (int kc = 0; kc < 4; ++kc)
#pragma unroll
        for (int gr = 0; gr < 3; ++gr) {
            int c = gr * 128 + g * 16 + (l & 15);
            size_t boff = (size_t)kc * 12288 + c * 32 + (l >> 4) * 8;
            BW[kc][gr] = ldbf8(&wcP[boff]);
            BU[kc][gr] = ldbf8(&whhP[boff]);
        }

    // staging + inline gather: each thread owns a 16B k-slice of one row
    {
        int row = row0 + srow;
        u16x8 uh = (u16x8){0,0,0,0,0,0,0,0};
        float g0[4] = {0.f, 0.f, 0.f, 0.f};
        float g1[4] = {0.f, 0.f, 0.f, 0.f};
        if (row < M) {
            size_t goff = (size_t)row * 128 + skc * 32 + skpos;
            uh = *(const u16x8*)&hbf[goff];
            int e0 = off[row], e1 = off[row + 1];
            int e = e0;
            for (; e + 1 < e1; e += 2) {
                int s0 = ssrc[e], s1 = ssrc[e + 1];
                uint4 v0 = *(const uint4*)&hbf[(size_t)s0 * 128 + skc * 32 + skpos];
                uint4 v1 = *(const uint4*)&hbf[(size_t)s1 * 128 + skc * 32 + skpos];
                g0[0] += bfbits_lo(v0.x); g0[1] += bfbits_hi(v0.x);
                g0[2] += bfbits_lo(v0.y); g0[3] += bfbits_hi(v0.y);
                g1[0] += bfbits_lo(v0.z); g1[1] += bfbits_hi(v0.z);
                g1[2] += bfbits_lo(v0.w); g1[3] += bfbits_hi(v0.w);
                g0[0] += bfbits_lo(v1.x); g0[1] += bfbits_hi(v1.x);
                g0[2] += bfbits_lo(v1.y); g0[3] += bfbits_hi(v1.y);
                g1[0] += bfbits_lo(v1.z); g1[1] += bfbits_hi(v1.z);
                g1[2] += bfbits_lo(v1.w); g1[3] += bfbits_hi(v1.w);
            }
            if (e < e1) {
                int s0 = ssrc[e];
                uint4 v0 = *(const uint4*)&hbf[(size_t)s0 * 128 + skc * 32 + skpos];
                g0[0] += bfbits_lo(v0.x); g0[1] += bfbits_hi(v0.x);
                g0[2] += bfbits_lo(v0.y); g0[3] += bfbits_hi(v0.y);
                g1[0] += bfbits_lo(v0.z); g1[1] += bfbits_hi(v0.z);
                g1[2] += bfbits_lo(v0.w); g1[3] += bfbits_hi(v0.w);
            }
        }
        u16x8 ua;
        ua[0] = f2bf(g0[0]); ua[1] = f2bf(g0[1]);
        ua[2] = f2bf(g0[2]); ua[3] = f2bf(g0[3]);
        ua[4] = f2bf(g1[0]); ua[5] = f2bf(g1[1]);
        ua[6] = f2bf(g1[2]); ua[7] = f2bf(g1[3]);
        *(u16x8*)((char*)Aa + slbyte) = ua;
        *(u16x8*)((char*)Ah + slbyte) = uh;
    }
    __syncthreads();

    f32x4 gi[3][2], gh[3][2];
#pragma unroll
    for (int gr = 0; gr < 3; ++gr)
#pragma unroll
        for (int rt = 0; rt < 2; ++rt) {
            gi[gr][rt] = (f32x4){0.f, 0.f, 0.f, 0.f};
            gh[gr][rt] = (f32x4){0.f, 0.f, 0.f, 0.f};
        }

#pragma unroll
    for (int kc = 0; kc < 4; ++kc) {
        bf16x8 aa[2], ah[2];
#pragma unroll
        for (int rt = 0; rt < 2; ++rt) {
            int lbyte = kc * 2048 + swzB(rt * 16 + (l & 15), l >> 4);
            aa[rt] = *(const bf16x8*)((const char*)Aa + lbyte);
            ah[rt] = *(const bf16x8*)((const char*)Ah + lbyte);
        }
#pragma unroll
        for (int gr = 0; gr < 3; ++gr)
#pragma unroll
            for (int rt = 0; rt < 2; ++rt) {
                gi[gr][rt] = __builtin_amdgcn_mfma_f32_16x16x32_bf16(aa[rt], BW[kc][gr], gi[gr][rt], 0, 0, 0);
                gh[gr][rt] = __builtin_amdgcn_mfma_f32_16x16x32_bf16(ah[rt], BU[kc][gr], gh[gr][rt], 0, 0, 0);
            }
    }

    // GRU epilogue; hv from staged Ah tile
#pragma unroll
    for (int rt = 0; rt < 2; ++rt)
#pragma unroll
        for (int j = 0; j < 4; ++j) {
            int rl = rt * 16 + (l >> 4) * 4 + j;
            int row = row0 + rl;
            if (row >= M) continue;
            float hv = bf2f(*(const unsigned short*)
                            ((const char*)Ah + kcu * 2048 + swzB(rl, slotu) + elemu * 2));
            float rr = fsigmoid(gi[0][rt][j] + bir + gh[0][rt][j] + bhr);
            float z  = fsigmoid(gi[1][rt][j] + biz + gh[1][rt][j] + bhz);
            float nn = ftanh(gi[2][rt][j] + bin + rr * (gh[2][rt][j] + bhn));
            float o  = (1.0f - z) * nn + z * hv;
            if (ELU) o = (o > 0.0f) ? o : (__expf(o) - 1.0f);
            if (OUTF32) hout[(size_t)row * 128 + unit] = o;
            else        houtbf[(size_t)row * 128 + unit] = f2bf(o);
        }
}

// ---------------- atomic-free two-level bucketed CSR build ----------------
// bucket = dst >> 8 ; chunk = 4096 edges. bh[chunk][256] histogram matrix.

#define CHUNK 4096

__global__ __launch_bounds__(1024)
void chunk_hist_kernel(const int* __restrict__ dst, int* __restrict__ bh, int E)
{
    __shared__ int lh[256];
    const int c = blockIdx.x, tid = threadIdx.x;
    if (tid < 256) lh[tid] = 0;
    __syncthreads();
#pragma unroll
    for (int q = 0; q < 4; ++q) {
        int e = c * CHUNK + q * 1024 + tid;
        if (e < E) atomicAdd(&lh[dst[e] >> 8], 1);
    }
    __syncthreads();
    if (tid < 256) bh[c * 256 + tid] = lh[tid];
}

__global__ __launch_bounds__(256)
void colscan_kernel(int* __restrict__ bh, int* __restrict__ bcnt, int NCH)
{
    __shared__ int wt[4];
    __shared__ int carry;
    const int b = blockIdx.x;
    const int tid = threadIdx.x, lane = tid & 63, w4 = tid >> 6;
    if (tid == 0) carry = 0;
    __syncthreads();
    for (int base = 0; base < NCH; base += 256) {
        int c = base + tid;
        int v = (c < NCH) ? bh[c * 256 + b] : 0;
        int s = v;
#pragma unroll
        for (int o = 1; o < 64; o <<= 1) {
            int n = __shfl_up(s, o, 64);
            if (lane >= o) s += n;
        }
        if (lane == 63) wt[w4] = s;
        __syncthreads();
        int wpre = 0;
        for (int q = 0; q < w4; ++q) wpre += wt[q];
        int ex = carry + wpre + s - v;
        if (c < NCH) bh[c * 256 + b] = ex;
        __syncthreads();
        if (tid == 255) carry = ex + v;
        __syncthreads();
    }
    if (tid == 0) bcnt[b] = carry;
}

__global__ __launch_bounds__(256)
void bscan2_kernel(const int* __restrict__ bcnt, int* __restrict__ bbase,
                   int* __restrict__ off, int N, int E)
{
    __shared__ int wt[4];
    const int tid = threadIdx.x, lane = tid & 63, w4 = tid >> 6;
    int v = bcnt[tid];
    int s = v;
#pragma unroll
    for (int o = 1; o < 64; o <<= 1) {
        int n = __shfl_up(s, o, 64);
        if (lane >= o) s += n;
    }
    if (lane == 63) wt[w4] = s;
    __syncthreads();
    int wpre = 0;
    for (int q = 0; q < w4; ++q) wpre += wt[q];
    bbase[tid] = wpre + s - v;
    if (tid == 0) off[N] = E;
}

__global__ __launch_bounds__(1024)
void place_kernel(const int* __restrict__ src, const int* __restrict__ dst,
                  const int* __restrict__ bh, const int* __restrict__ bbase,
                  unsigned long long* __restrict__ bpair, int E)
{
    __shared__ int cur[256];
    const int c = blockIdx.x, tid = threadIdx.x;
    if (tid < 256) cur[tid] = bbase[tid] + bh[c * 256 + tid];
    __syncthreads();
#pragma unroll
    for (int q = 0; q < 4; ++q) {
        int e = c * CHUNK + q * 1024 + tid;
        if (e < E) {
            int d = dst[e];
            int pos = atomicAdd(&cur[d >> 8], 1);
            bpair[(size_t)pos] = ((unsigned long long)(unsigned)d << 32) | (unsigned)src[e];
        }
    }
}

__global__ __launch_bounds__(1024)
void bucket_sort_kernel(const unsigned long long* __restrict__ bpair,
                        const int* __restrict__ bcnt, const int* __restrict__ bbase,
                        int* __restrict__ off, int* __restrict__ ssrc, int N)
{
    __shared__ int hist[256];
    __shared__ int wt[4];
    const int b = blockIdx.x;
    const int tid = threadIdx.x;
    const int cnt = bcnt[b];
    const int base = bbase[b];

    if (tid < 256) hist[tid] = 0;
    __syncthreads();
    for (int i = tid; i < cnt; i += 1024) {
        unsigned long long p = bpair[(size_t)base + i];
        atomicAdd(&hist[(int)(p >> 32) & 255], 1);
    }
    __syncthreads();

    int ex = 0;
    {
        int lane = tid & 63, w4 = tid >> 6;
        int v = (tid < 256) ? hist[tid] : 0;
        int s = v;
#pragma unroll
        for (int o = 1; o < 64; o <<= 1) {
            int n = __shfl_up(s, o, 64);
            if (lane >= o) s += n;
        }
        if (tid < 256 && lane == 63) wt[w4] = s;
        __syncthreads();
        if (tid < 256) {
            int wpre = 0;
            for (int q = 0; q < w4; ++q) wpre += wt[q];
            ex = wpre + s - v;
        }
    }
    __syncthreads();
    if (tid < 256) {
        int d = (b << 8) + tid;
        if (d < N) off[d] = base + ex;
        hist[tid] = ex;            // reuse as cursor
    }
    __syncthreads();
    for (int i = tid; i < cnt; i += 1024) {
        unsigned long long p = bpair[(size_t)base + i];
        int d = (int)(p >> 32) & 255;
        int pos = atomicAdd(&hist[d], 1);
        ssrc[(size_t)base + pos] = (int)(unsigned)p;
    }
}

// one wave per node: logits = h@W + b ; log_softmax ; per-block partial loss
__global__ __launch_bounds__(256)
void cls_kernel(const float* __restrict__ h, const float* __restrict__ W,
                const float* __restrict__ b, const int* __restrict__ y,
                float* __restrict__ logitsOut, float* __restrict__ partials,
                int N, float invN)
{
    __shared__ float pl[4];
    const int wid  = threadIdx.x >> 6;
    const int lane = threadIdx.x & 63;
    const int gw   = blockIdx.x * 4 + wid;
    if (threadIdx.x < 4) pl[threadIdx.x] = 0.0f;
    __syncthreads();
    if (gw < N) {
        float h0 = h[(size_t)gw * 128 + lane * 2];
        float h1 = h[(size_t)gw * 128 + lane * 2 + 1];
        float acc[6];
#pragma unroll
        for (int c = 0; c < 6; ++c)
            acc[c] = h0 * W[(lane * 2) * 6 + c] + h1 * W[(lane * 2 + 1) * 6 + c];
#pragma unroll
        for (int off = 32; off >= 1; off >>= 1)
#pragma unroll
            for (int c = 0; c < 6; ++c)
                acc[c] += __shfl_xor(acc[c], off, 64);
        float logit[6];
#pragma unroll
        for (int c = 0; c < 6; ++c) logit[c] = acc[c] + b[c];
#pragma unroll
        for (int c = 0; c < 6; ++c)
            if (lane == c) logitsOut[(size_t)gw * 6 + c] = logit[c];
        if (lane == 0) {
            float mx = logit[0];
#pragma unroll
            for (int c = 1; c < 6; ++c) mx = fmaxf(mx, logit[c]);
            float se = 0.0f;
#pragma unroll
            for (int c = 0; c < 6; ++c) se += expf(logit[c] - mx);
            float lse = mx + logf(se);
            int yy = y[gw];
            float ly = 0.0f;
#pragma unroll
            for (int c = 0; c < 6; ++c)
                if (yy == c) ly = logit[c];
            pl[wid] = (lse - ly) * invN;
        }
    }
    __syncthreads();
    if (threadIdx.x == 0)
        partials[blockIdx.x] = pl[0] + pl[1] + pl[2] + pl[3];
}

__global__ __launch_bounds__(1024)
void loss_reduce(const float* __restrict__ partials, float* __restrict__ loss, int P)
{
    __shared__ float buf[1024];
    float s = 0.0f;
    for (int i = threadIdx.x; i < (unsigned)P; i += 1024) s += partials[i];
    buf[threadIdx.x] = s;
    __syncthreads();
    for (int o = 512; o >= 1; o >>= 1) {
        if (threadIdx.x < (unsigned)o) buf[threadIdx.x] += buf[threadIdx.x + o];
        __syncthreads();
    }
    if (threadIdx.x == 0) loss[0] = buf[0];
}

extern "C" void kernel_launch(void* const* d_in, const int* in_sizes, int n_in,
                              void* d_out, int out_size, void* d_ws, size_t ws_size,
                              hipStream_t stream)
{
    const float* x     = (const float*)d_in[0];
    const int*   eidx  = (const int*)d_in[1];
    const int*   y     = (const int*)d_in[2];
    const float* lin_w = (const float*)d_in[3];
    const float* lin_b = (const float*)d_in[4];
    const float* w1    = (const float*)d_in[5];
    const float* wih1  = (const float*)d_in[6];
    const float* whh1  = (const float*)d_in[7];
    const float* bih1  = (const float*)d_in[8];
    const float* bhh1  = (const float*)d_in[9];
    const float* w2    = (const float*)d_in[10];
    const float* wih2  = (const float*)d_in[11];
    const float* whh2  = (const float*)d_in[12];
    const float* bih2  = (const float*)d_in[13];
    const float* bhh2  = (const float*)d_in[14];
    const float* cls_w = (const float*)d_in[15];
    const float* cls_b = (const float*)d_in[16];

    const int N   = in_sizes[2];
    const int E   = in_sizes[1] / 2;
    const int L   = 6;
    const size_t NH = (size_t)N * 128;
    const int P   = (N + 3) / 4;
    const int NT  = (N + 31) / 32;       // gru row tiles
    const int NCH = (E + CHUNK - 1) / CHUNK;
    const int NBK = (N + 255) >> 8;

    float* out    = (float*)d_out;
    float* logits = out;
    float* loss   = out + (size_t)N * L;
    float* feats  = out + (size_t)N * L + 1;

    float* ws   = (float*)d_ws;
    float* part = ws;                 // P f32

    unsigned short* h_bf   = (unsigned short*)(part + P);  // NH bf16 (layer0 out / layer1 in)
    unsigned short* hb2    = h_bf + NH;                    // NH bf16 (layer1 out / layer2 in)
    unsigned short* linP   = hb2 + NH;                     // 256*128
    unsigned short* wc1P   = linP  + 32768;                // [4][384][32]
    unsigned short* whh1P  = wc1P  + 49152;
    unsigned short* wc2P   = whh1P + 49152;
    unsigned short* whh2P  = wc2P  + 49152;

    int* off   = (int*)(whh2P + 49152);    // N+1 (+1 pad)
    int* bcnt  = off + (N + 2);            // 256
    int* bbase = bcnt + 256;               // 256
    int* bh    = bbase + 256;              // NCH*256
    unsigned long long* bpair =
        (unsigned long long*)(((uintptr_t)(bh + (size_t)NCH * 256) + 7) & ~(uintptr_t)7);  // E
    int* ssrc  = (int*)(bpair + E);        // E

    const int* src = eidx;
    const int* dst = eidx + E;

    dim3 blk(256);
    unsigned ngridW = (unsigned)((N + 3) / 4);
    unsigned gemmG  = (unsigned)((N + 63) / 64);

    // ---- atomic-free bucketed CSR build (once; reused by both layers) ----
    chunk_hist_kernel<<<dim3((unsigned)NCH), dim3(1024), 0, stream>>>(dst, bh, E);
    colscan_kernel<<<dim3(256), dim3(256), 0, stream>>>(bh, bcnt, NCH);
    bscan2_kernel<<<dim3(1), dim3(256), 0, stream>>>(bcnt, bbase, off, N, E);
    place_kernel<<<dim3((unsigned)NCH), dim3(1024), 0, stream>>>(src, dst, bh, bbase, bpair, E);
    bucket_sort_kernel<<<dim3((unsigned)NBK), dim3(1024), 0, stream>>>(bpair, bcnt, bbase, off, ssrc, N);

    // weight prep: lin projection pack, combined Wc = w@wih^T, whh pack
    prepack_kernel<<<dim3(128), blk, 0, stream>>>(lin_w, linP, 256, 128, 0);
    wcomb_kernel<<<dim3(192), blk, 0, stream>>>(w1, wih1, wc1P);
    wcomb_kernel<<<dim3(192), blk, 0, stream>>>(w2, wih2, wc2P);
    prepack_kernel<<<dim3(192), blk, 0, stream>>>(whh1, whh1P, 128, 384, 1);
    prepack_kernel<<<dim3(192), blk, 0, stream>>>(whh2, whh2P, 128, 384, 1);

    // h_bf = bf16(x @ lin_w + lin_b)
    mfma_xw<8><<<dim3(gemmG), blk, 0, stream>>>(x, linP, lin_b, h_bf, N);

    // ---- layer 1: fused gather+GRU, h_bf -> hb2 (ping-pong, no in-place race) ----
    mfma_gru<1, 0><<<dim3((unsigned)NT), dim3(512), 0, stream>>>(off, ssrc, h_bf, wc1P, whh1P, bih1, bhh1, nullptr, hb2, N);

    // ---- layer 2: fused gather+GRU, hb2 -> feats (f32) ----
    mfma_gru<0, 1><<<dim3((unsigned)NT), dim3(512), 0, stream>>>(off, ssrc, hb2, wc2P, whh2P, bih2, bhh2, feats, nullptr, N);

    // ---- classifier + loss ----
    cls_kernel<<<dim3(ngridW), blk, 0, stream>>>(feats, cls_w, cls_b, y, logits, part, N, 1.0f / (float)N);
    loss_reduce<<<dim3(1), dim3(1024), 0, stream>>>(part, loss, P);
}

// Round 20
// 228.851 us; speedup vs baseline: 1.3387x; 1.3387x over previous
//
#include <hip/hip_runtime.h>
#include <cstddef>
#include <cstdint>

typedef __attribute__((ext_vector_type(8))) short bf16x8;
typedef __attribute__((ext_vector_type(4))) float f32x4;
typedef __attribute__((ext_vector_type(8))) unsigned short u16x8;

__device__ inline unsigned short f2bf(float f) {
    unsigned u = __builtin_bit_cast(unsigned, f);
    u += 0x7FFF + ((u >> 16) & 1);          // round-to-nearest-even
    return (unsigned short)(u >> 16);
}
__device__ inline float bfbits_lo(unsigned v) { return __builtin_bit_cast(float, v << 16); }
__device__ inline float bfbits_hi(unsigned v) { return __builtin_bit_cast(float, v & 0xffff0000u); }
__device__ inline float bf2f(unsigned short b) { return __builtin_bit_cast(float, (unsigned)b << 16); }

// fast device math (v_exp_f32 / v_rcp_f32 paths)
__device__ inline float fsigmoid(float x) { return 1.0f / (1.0f + __expf(-x)); }
__device__ inline float ftanh(float x)    { return 1.0f - 2.0f / (__expf(2.0f * x) + 1.0f); }

// XOR-swizzled byte offset into a [rows][32 bf16] LDS tile (64B rows).
__device__ inline int swzB(int row, int slot) {
    return row * 64 + ((slot ^ ((row >> 1) & 3)) << 4);
}
__device__ inline bf16x8 ldbf8(const unsigned short* p) {
    u16x8 v = *(const u16x8*)p;
    return __builtin_bit_cast(bf16x8, v);
}

// ---------------- weight prepack: P[kc][c][kk] = Bop[k=kc*32+kk][c] ----------------
__global__ __launch_bounds__(256)
void prepack_kernel(const float* __restrict__ S, unsigned short* __restrict__ P,
                    int K, int C, int trans)
{
    int idx = blockIdx.x * 256 + threadIdx.x;
    if (idx >= K * C) return;
    int kk = idx & 31;
    int c  = (idx >> 5) % C;
    int kc = idx / (32 * C);
    int k  = kc * 32 + kk;
    float v = trans ? S[(size_t)c * K + k] : S[(size_t)k * C + c];
    P[idx] = f2bf(v);
}

// ---------------- combined weight: Wc = Wm @ Wih^T, packed [kc][c:384][kk] ----------------
__global__ __launch_bounds__(256)
void wcomb_kernel(const float* __restrict__ Wm, const float* __restrict__ Wih,
                  unsigned short* __restrict__ P)
{
    int idx = blockIdx.x * 256 + threadIdx.x;   // 4*384*32 = 49152
    int kk = idx & 31;
    int c  = (idx >> 5) % 384;
    int kc = idx / (32 * 384);
    int d  = kc * 32 + kk;
    const float4* a = (const float4*)&Wm[(size_t)d * 128];
    const float4* b = (const float4*)&Wih[(size_t)c * 128];
    float s = 0.0f;
#pragma unroll 8
    for (int t = 0; t < 32; ++t) {
        float4 av = a[t], bv = b[t];
        s += av.x * bv.x + av.y * bv.y + av.z * bv.z + av.w * bv.w;
    }
    P[idx] = f2bf(s);
}

// ---------------- MFMA GEMM (input projection): h_bf = bf16(x@linW + b) ----------------
template<int KC>
__global__ __launch_bounds__(256)
void mfma_xw(const float* __restrict__ A, const unsigned short* __restrict__ P,
             const float* __restrict__ bias, unsigned short* __restrict__ Cbf, int M)
{
    __shared__ unsigned short Ab[KC * 2048];   // [kc][64 rows][32 k], swizzled per kc
    const int tid  = threadIdx.x;
    const int l    = tid & 63;
    const int w    = tid >> 6;
    const int wr   = w >> 1, wc = w & 1;
    const int row0 = blockIdx.x * 64;
    const int K    = KC * 32;

    {
        int row = tid >> 2, slot = tid & 3, kpos = slot * 8;
#pragma unroll
        for (int kc = 0; kc < KC; ++kc) {
            unsigned short u[8];
            if (row0 + row < M) {
                const float* src = &A[(size_t)(row0 + row) * K + kc * 32 + kpos];
                float4 v0 = *(const float4*)src;
                float4 v1 = *(const float4*)(src + 4);
                u[0]=f2bf(v0.x); u[1]=f2bf(v0.y); u[2]=f2bf(v0.z); u[3]=f2bf(v0.w);
                u[4]=f2bf(v1.x); u[5]=f2bf(v1.y); u[6]=f2bf(v1.z); u[7]=f2bf(v1.w);
            } else {
#pragma unroll
                for (int q = 0; q < 8; ++q) u[q] = 0;
            }
            *(u16x8*)((char*)Ab + kc * 4096 + swzB(row, slot)) = *(u16x8*)u;
        }
    }
    __syncthreads();

    f32x4 acc[2][4];
#pragma unroll
    for (int i = 0; i < 2; ++i)
#pragma unroll
        for (int j = 0; j < 4; ++j) acc[i][j] = (f32x4){0.f, 0.f, 0.f, 0.f};

#pragma unroll
    for (int kc = 0; kc < KC; ++kc) {
        bf16x8 af[2], bf[4];
#pragma unroll
        for (int rt = 0; rt < 2; ++rt)
            af[rt] = *(const bf16x8*)((const char*)Ab + kc * 4096 +
                                      swzB(wr * 32 + rt * 16 + (l & 15), l >> 4));
#pragma unroll
        for (int ct = 0; ct < 4; ++ct) {
            int c = wc * 64 + ct * 16 + (l & 15);
            bf[ct] = ldbf8(&P[(size_t)kc * 4096 + c * 32 + (l >> 4) * 8]);
        }
#pragma unroll
        for (int rt = 0; rt < 2; ++rt)
#pragma unroll
            for (int ct = 0; ct < 4; ++ct)
                acc[rt][ct] = __builtin_amdgcn_mfma_f32_16x16x32_bf16(af[rt], bf[ct], acc[rt][ct], 0, 0, 0);
    }

#pragma unroll
    for (int rt = 0; rt < 2; ++rt)
#pragma unroll
        for (int ct = 0; ct < 4; ++ct) {
            int col = wc * 64 + ct * 16 + (l & 15);
            float bv = bias ? bias[col] : 0.0f;
#pragma unroll
            for (int j = 0; j < 4; ++j) {
                int row = row0 + wr * 32 + rt * 16 + (l >> 4) * 4 + j;
                if (row < M) Cbf[(size_t)row * 128 + col] = f2bf(acc[rt][ct][j] + bv);
            }
        }
}

// ---------------- fused gi/gh GEMMs + GRU, B-in-registers, grid-stride tiles ----------------
template<int ELU, int OUTF32>
__global__ __launch_bounds__(512, 2)
void mfma_gru(const unsigned short* __restrict__ agghbf, const unsigned short* __restrict__ hbf,
              const unsigned short* __restrict__ wcP, const unsigned short* __restrict__ whhP,
              const float* __restrict__ bih, const float* __restrict__ bhh,
              float* __restrict__ hout, unsigned short* __restrict__ houtbf,
              int M, int ntiles)
{
    __shared__ unsigned short Aa[4096];   // [kc][32 rows][32 k] swizzled, 8KB
    __shared__ unsigned short Ah[4096];
    const int tid = threadIdx.x;
    const int l   = tid & 63;
    const int g   = tid >> 6;             // wave = unit group

    const int skc = tid >> 7;             // staging kc
    const int t3  = tid & 127;
    const int srow = t3 >> 2, sslot = t3 & 3, skpos = sslot * 8;
    const int slbyte = skc * 2048 + swzB(srow, sslot);

    const int unit = g * 16 + (l & 15);
    const int kcu = unit >> 5, slotu = (unit & 31) >> 3, elemu = unit & 7;
    const float bir = bih[unit], biz = bih[128 + unit], bin = bih[256 + unit];
    const float bhr = bhh[unit], bhz = bhh[128 + unit], bhn = bhh[256 + unit];

    // B fragments in registers (block-invariant): 24 x bf16x8 = 96 VGPR
    bf16x8 BW[4][3], BU[4][3];
#pragma unroll
    for (int kc = 0; kc < 4; ++kc)
#pragma unroll
        for (int gr = 0; gr < 3; ++gr) {
            int c = gr * 128 + g * 16 + (l & 15);
            size_t boff = (size_t)kc * 12288 + c * 32 + (l >> 4) * 8;
            BW[kc][gr] = ldbf8(&wcP[boff]);
            BU[kc][gr] = ldbf8(&whhP[boff]);
        }

    u16x8 ua = (u16x8){0,0,0,0,0,0,0,0};
    u16x8 uh = (u16x8){0,0,0,0,0,0,0,0};
    {
        int row0 = blockIdx.x * 32;
        if (row0 + srow < M && row0 < ntiles * 32) {
            size_t goff = (size_t)(row0 + srow) * 128 + skc * 32 + skpos;
            ua = *(const u16x8*)&agghbf[goff];
            uh = *(const u16x8*)&hbf[goff];
        }
    }

    for (int t = blockIdx.x; t < ntiles; t += gridDim.x) {
        const int row0 = t * 32;
        __syncthreads();
        *(u16x8*)((char*)Aa + slbyte) = ua;
        *(u16x8*)((char*)Ah + slbyte) = uh;
        __syncthreads();

        {
            int tn = t + gridDim.x;
            ua = (u16x8){0,0,0,0,0,0,0,0};
            uh = (u16x8){0,0,0,0,0,0,0,0};
            if (tn < ntiles) {
                int r0n = tn * 32;
                if (r0n + srow < M) {
                    size_t goff = (size_t)(r0n + srow) * 128 + skc * 32 + skpos;
                    ua = *(const u16x8*)&agghbf[goff];
                    uh = *(const u16x8*)&hbf[goff];
                }
            }
        }

        f32x4 gi[3][2], gh[3][2];
#pragma unroll
        for (int gr = 0; gr < 3; ++gr)
#pragma unroll
            for (int rt = 0; rt < 2; ++rt) {
                gi[gr][rt] = (f32x4){0.f, 0.f, 0.f, 0.f};
                gh[gr][rt] = (f32x4){0.f, 0.f, 0.f, 0.f};
            }

#pragma unroll
        for (int kc = 0; kc < 4; ++kc) {
            bf16x8 aa[2], ah[2];
#pragma unroll
            for (int rt = 0; rt < 2; ++rt) {
                int lbyte = kc * 2048 + swzB(rt * 16 + (l & 15), l >> 4);
                aa[rt] = *(const bf16x8*)((const char*)Aa + lbyte);
                ah[rt] = *(const bf16x8*)((const char*)Ah + lbyte);
            }
#pragma unroll
            for (int gr = 0; gr < 3; ++gr)
#pragma unroll
                for (int rt = 0; rt < 2; ++rt) {
                    gi[gr][rt] = __builtin_amdgcn_mfma_f32_16x16x32_bf16(aa[rt], BW[kc][gr], gi[gr][rt], 0, 0, 0);
                    gh[gr][rt] = __builtin_amdgcn_mfma_f32_16x16x32_bf16(ah[rt], BU[kc][gr], gh[gr][rt], 0, 0, 0);
                }
        }

#pragma unroll
        for (int rt = 0; rt < 2; ++rt)
#pragma unroll
            for (int j = 0; j < 4; ++j) {
                int rl = rt * 16 + (l >> 4) * 4 + j;
                int row = row0 + rl;
                if (row >= M) continue;
                float hv = bf2f(*(const unsigned short*)
                                ((const char*)Ah + kcu * 2048 + swzB(rl, slotu) + elemu * 2));
                float rr = fsigmoid(gi[0][rt][j] + bir + gh[0][rt][j] + bhr);
                float z  = fsigmoid(gi[1][rt][j] + biz + gh[1][rt][j] + bhz);
                float nn = ftanh(gi[2][rt][j] + bin + rr * (gh[2][rt][j] + bhn));
                float o  = (1.0f - z) * nn + z * hv;
                if (ELU) o = (o > 0.0f) ? o : (__expf(o) - 1.0f);
                if (OUTF32) hout[(size_t)row * 128 + unit] = o;
                else        houtbf[(size_t)row * 128 + unit] = f2bf(o);
            }
    }
}

// ---------------- atomic-free two-level bucketed CSR build ----------------
// bucket = dst >> 8 ; chunk = 4096 edges. bh[chunk][256] histogram matrix.

#define CHUNK 4096

__global__ __launch_bounds__(1024)
void chunk_hist_kernel(const int* __restrict__ dst, int* __restrict__ bh, int E)
{
    __shared__ int lh[256];
    const int c = blockIdx.x, tid = threadIdx.x;
    if (tid < 256) lh[tid] = 0;
    __syncthreads();
#pragma unroll
    for (int q = 0; q < 4; ++q) {
        int e = c * CHUNK + q * 1024 + tid;
        if (e < E) atomicAdd(&lh[dst[e] >> 8], 1);
    }
    __syncthreads();
    if (tid < 256) bh[c * 256 + tid] = lh[tid];
}

__global__ __launch_bounds__(256)
void colscan_kernel(int* __restrict__ bh, int* __restrict__ bcnt, int NCH)
{
    __shared__ int wt[4];
    __shared__ int carry;
    const int b = blockIdx.x;
    const int tid = threadIdx.x, lane = tid & 63, w4 = tid >> 6;
    if (tid == 0) carry = 0;
    __syncthreads();
    for (int base = 0; base < NCH; base += 256) {
        int c = base + tid;
        int v = (c < NCH) ? bh[c * 256 + b] : 0;
        int s = v;
#pragma unroll
        for (int o = 1; o < 64; o <<= 1) {
            int n = __shfl_up(s, o, 64);
            if (lane >= o) s += n;
        }
        if (lane == 63) wt[w4] = s;
        __syncthreads();
        int wpre = 0;
        for (int q = 0; q < w4; ++q) wpre += wt[q];
        int ex = carry + wpre + s - v;
        if (c < NCH) bh[c * 256 + b] = ex;
        __syncthreads();
        if (tid == 255) carry = ex + v;
        __syncthreads();
    }
    if (tid == 0) bcnt[b] = carry;
}

__global__ __launch_bounds__(256)
void bscan2_kernel(const int* __restrict__ bcnt, int* __restrict__ bbase,
                   int* __restrict__ off, int N, int E)
{
    __shared__ int wt[4];
    const int tid = threadIdx.x, lane = tid & 63, w4 = tid >> 6;
    int v = bcnt[tid];
    int s = v;
#pragma unroll
    for (int o = 1; o < 64; o <<= 1) {
        int n = __shfl_up(s, o, 64);
        if (lane >= o) s += n;
    }
    if (lane == 63) wt[w4] = s;
    __syncthreads();
    int wpre = 0;
    for (int q = 0; q < w4; ++q) wpre += wt[q];
    bbase[tid] = wpre + s - v;
    if (tid == 0) off[N] = E;
}

__global__ __launch_bounds__(1024)
void place_kernel(const int* __restrict__ src, const int* __restrict__ dst,
                  const int* __restrict__ bh, const int* __restrict__ bbase,
                  unsigned long long* __restrict__ bpair, int E)
{
    __shared__ int cur[256];
    const int c = blockIdx.x, tid = threadIdx.x;
    if (tid < 256) cur[tid] = bbase[tid] + bh[c * 256 + tid];
    __syncthreads();
#pragma unroll
    for (int q = 0; q < 4; ++q) {
        int e = c * CHUNK + q * 1024 + tid;
        if (e < E) {
            int d = dst[e];
            int pos = atomicAdd(&cur[d >> 8], 1);
            bpair[(size_t)pos] = ((unsigned long long)(unsigned)d << 32) | (unsigned)src[e];
        }
    }
}

__global__ __launch_bounds__(1024)
void bucket_sort_kernel(const unsigned long long* __restrict__ bpair,
                        const int* __restrict__ bcnt, const int* __restrict__ bbase,
                        int* __restrict__ off, int* __restrict__ ssrc, int N)
{
    __shared__ int hist[256];
    __shared__ int wt[4];
    const int b = blockIdx.x;
    const int tid = threadIdx.x;
    const int cnt = bcnt[b];
    const int base = bbase[b];

    if (tid < 256) hist[tid] = 0;
    __syncthreads();
    for (int i = tid; i < cnt; i += 1024) {
        unsigned long long p = bpair[(size_t)base + i];
        atomicAdd(&hist[(int)(p >> 32) & 255], 1);
    }
    __syncthreads();

    int ex = 0;
    {
        int lane = tid & 63, w4 = tid >> 6;
        int v = (tid < 256) ? hist[tid] : 0;
        int s = v;
#pragma unroll
        for (int o = 1; o < 64; o <<= 1) {
            int n = __shfl_up(s, o, 64);
            if (lane >= o) s += n;
        }
        if (tid < 256 && lane == 63) wt[w4] = s;
        __syncthreads();
        if (tid < 256) {
            int wpre = 0;
            for (int q = 0; q < w4; ++q) wpre += wt[q];
            ex = wpre + s - v;
        }
    }
    __syncthreads();
    if (tid < 256) {
        int d = (b << 8) + tid;
        if (d < N) off[d] = base + ex;
        hist[tid] = ex;            // reuse as cursor
    }
    __syncthreads();
    for (int i = tid; i < cnt; i += 1024) {
        unsigned long long p = bpair[(size_t)base + i];
        int d = (int)(p >> 32) & 255;
        int pos = atomicAdd(&hist[d], 1);
        ssrc[(size_t)base + pos] = (int)(unsigned)p;
    }
}

// one wave per dst node, bf16 rows: aggh[n] = sum of hbf[ssrc[e]] rows.
__global__ __launch_bounds__(256)
void gather_agg_bf(const unsigned short* __restrict__ m, const int* __restrict__ off,
                   const int* __restrict__ ssrc, unsigned short* __restrict__ agg, int N)
{
    int w = (blockIdx.x * 256 + threadIdx.x) >> 6;
    int lane = threadIdx.x & 63;
    if (w >= N) return;
    int half = lane >> 5, hl = lane & 31;
    int e0 = off[w], e1 = off[w + 1];
    float a0[4] = {0.f, 0.f, 0.f, 0.f};
    float a1[4] = {0.f, 0.f, 0.f, 0.f};
    int e = e0 + half;
    for (; e + 2 < e1; e += 4) {
        int s0 = ssrc[e], s1 = ssrc[e + 2];
        uint2 v0 = *(const uint2*)&m[(size_t)s0 * 128 + hl * 4];
        uint2 v1 = *(const uint2*)&m[(size_t)s1 * 128 + hl * 4];
        a0[0] += bfbits_lo(v0.x); a0[1] += bfbits_hi(v0.x);
        a0[2] += bfbits_lo(v0.y); a0[3] += bfbits_hi(v0.y);
        a1[0] += bfbits_lo(v1.x); a1[1] += bfbits_hi(v1.x);
        a1[2] += bfbits_lo(v1.y); a1[3] += bfbits_hi(v1.y);
    }
    if (e < e1) {
        int s0 = ssrc[e];
        uint2 v0 = *(const uint2*)&m[(size_t)s0 * 128 + hl * 4];
        a0[0] += bfbits_lo(v0.x); a0[1] += bfbits_hi(v0.x);
        a0[2] += bfbits_lo(v0.y); a0[3] += bfbits_hi(v0.y);
    }
    float o[4];
#pragma unroll
    for (int j = 0; j < 4; ++j) o[j] = a0[j] + a1[j];
#pragma unroll
    for (int j = 0; j < 4; ++j) o[j] += __shfl_xor(o[j], 32, 64);
    if (half == 0) {
        uint2 pk;
        pk.x = (unsigned)f2bf(o[0]) | ((unsigned)f2bf(o[1]) << 16);
        pk.y = (unsigned)f2bf(o[2]) | ((unsigned)f2bf(o[3]) << 16);
        *(uint2*)&agg[(size_t)w * 128 + hl * 4] = pk;
    }
}

// one wave per node: logits = h@W + b ; log_softmax ; per-block partial loss
__global__ __launch_bounds__(256)
void cls_kernel(const float* __restrict__ h, const float* __restrict__ W,
                const float* __restrict__ b, const int* __restrict__ y,
                float* __restrict__ logitsOut, float* __restrict__ partials,
                int N, float invN)
{
    __shared__ float pl[4];
    const int wid  = threadIdx.x >> 6;
    const int lane = threadIdx.x & 63;
    const int gw   = blockIdx.x * 4 + wid;
    if (threadIdx.x < 4) pl[threadIdx.x] = 0.0f;
    __syncthreads();
    if (gw < N) {
        float h0 = h[(size_t)gw * 128 + lane * 2];
        float h1 = h[(size_t)gw * 128 + lane * 2 + 1];
        float acc[6];
#pragma unroll
        for (int c = 0; c < 6; ++c)
            acc[c] = h0 * W[(lane * 2) * 6 + c] + h1 * W[(lane * 2 + 1) * 6 + c];
#pragma unroll
        for (int off = 32; off >= 1; off >>= 1)
#pragma unroll
            for (int c = 0; c < 6; ++c)
                acc[c] += __shfl_xor(acc[c], off, 64);
        float logit[6];
#pragma unroll
        for (int c = 0; c < 6; ++c) logit[c] = acc[c] + b[c];
#pragma unroll
        for (int c = 0; c < 6; ++c)
            if (lane == c) logitsOut[(size_t)gw * 6 + c] = logit[c];
        if (lane == 0) {
            float mx = logit[0];
#pragma unroll
            for (int c = 1; c < 6; ++c) mx = fmaxf(mx, logit[c]);
            float se = 0.0f;
#pragma unroll
            for (int c = 0; c < 6; ++c) se += expf(logit[c] - mx);
            float lse = mx + logf(se);
            int yy = y[gw];
            float ly = 0.0f;
#pragma unroll
            for (int c = 0; c < 6; ++c)
                if (yy == c) ly = logit[c];
            pl[wid] = (lse - ly) * invN;
        }
    }
    __syncthreads();
    if (threadIdx.x == 0)
        partials[blockIdx.x] = pl[0] + pl[1] + pl[2] + pl[3];
}

__global__ __launch_bounds__(1024)
void loss_reduce(const float* __restrict__ partials, float* __restrict__ loss, int P)
{
    __shared__ float buf[1024];
    float s = 0.0f;
    for (int i = threadIdx.x; i < (unsigned)P; i += 1024) s += partials[i];
    buf[threadIdx.x] = s;
    __syncthreads();
    for (int o = 512; o >= 1; o >>= 1) {
        if (threadIdx.x < (unsigned)o) buf[threadIdx.x] += buf[threadIdx.x + o];
        __syncthreads();
    }
    if (threadIdx.x == 0) loss[0] = buf[0];
}

extern "C" void kernel_launch(void* const* d_in, const int* in_sizes, int n_in,
                              void* d_out, int out_size, void* d_ws, size_t ws_size,
                              hipStream_t stream)
{
    const float* x     = (const float*)d_in[0];
    const int*   eidx  = (const int*)d_in[1];
    const int*   y     = (const int*)d_in[2];
    const float* lin_w = (const float*)d_in[3];
    const float* lin_b = (const float*)d_in[4];
    const float* w1    = (const float*)d_in[5];
    const float* wih1  = (const float*)d_in[6];
    const float* whh1  = (const float*)d_in[7];
    const float* bih1  = (const float*)d_in[8];
    const float* bhh1  = (const float*)d_in[9];
    const float* w2    = (const float*)d_in[10];
    const float* wih2  = (const float*)d_in[11];
    const float* whh2  = (const float*)d_in[12];
    const float* bih2  = (const float*)d_in[13];
    const float* bhh2  = (const float*)d_in[14];
    const float* cls_w = (const float*)d_in[15];
    const float* cls_b = (const float*)d_in[16];

    const int N   = in_sizes[2];
    const int E   = in_sizes[1] / 2;
    const int L   = 6;
    const size_t NH = (size_t)N * 128;
    const int P   = (N + 3) / 4;
    const int NT  = (N + 31) / 32;       // gru row tiles
    const int NCH = (E + CHUNK - 1) / CHUNK;
    const int NBK = (N + 255) >> 8;

    float* out    = (float*)d_out;
    float* logits = out;
    float* loss   = out + (size_t)N * L;
    float* feats  = out + (size_t)N * L + 1;

    float* ws   = (float*)d_ws;
    float* part = ws;                 // P f32

    unsigned short* h_bf   = (unsigned short*)(part + P);  // NH bf16
    unsigned short* aggh   = h_bf + NH;                    // NH bf16
    unsigned short* linP   = aggh + NH;                    // 256*128
    unsigned short* wc1P   = linP  + 32768;                // [4][384][32]
    unsigned short* whh1P  = wc1P  + 49152;
    unsigned short* wc2P   = whh1P + 49152;
    unsigned short* whh2P  = wc2P  + 49152;

    int* off   = (int*)(whh2P + 49152);    // N+1 (+1 pad)
    int* bcnt  = off + (N + 2);            // 256
    int* bbase = bcnt + 256;               // 256
    int* bh    = bbase + 256;              // NCH*256
    unsigned long long* bpair =
        (unsigned long long*)(((uintptr_t)(bh + (size_t)NCH * 256) + 7) & ~(uintptr_t)7);  // E
    int* ssrc  = (int*)(bpair + E);        // E

    const int* src = eidx;
    const int* dst = eidx + E;

    dim3 blk(256);
    unsigned ngridW = (unsigned)((N + 3) / 4);
    unsigned gemmG  = (unsigned)((N + 63) / 64);
    unsigned gruG   = (unsigned)(NT < 256 ? NT : 256);

    // ---- atomic-free bucketed CSR build (once; reused by both layers) ----
    chunk_hist_kernel<<<dim3((unsigned)NCH), dim3(1024), 0, stream>>>(dst, bh, E);
    colscan_kernel<<<dim3(256), dim3(256), 0, stream>>>(bh, bcnt, NCH);
    bscan2_kernel<<<dim3(1), dim3(256), 0, stream>>>(bcnt, bbase, off, N, E);
    place_kernel<<<dim3((unsigned)NCH), dim3(1024), 0, stream>>>(src, dst, bh, bbase, bpair, E);
    bucket_sort_kernel<<<dim3((unsigned)NBK), dim3(1024), 0, stream>>>(bpair, bcnt, bbase, off, ssrc, N);

    // weight prep: lin projection pack, combined Wc = w@wih^T, whh pack
    prepack_kernel<<<dim3(128), blk, 0, stream>>>(lin_w, linP, 256, 128, 0);
    wcomb_kernel<<<dim3(192), blk, 0, stream>>>(w1, wih1, wc1P);
    wcomb_kernel<<<dim3(192), blk, 0, stream>>>(w2, wih2, wc2P);
    prepack_kernel<<<dim3(192), blk, 0, stream>>>(whh1, whh1P, 128, 384, 1);
    prepack_kernel<<<dim3(192), blk, 0, stream>>>(whh2, whh2P, 128, 384, 1);

    // h_bf = bf16(x @ lin_w + lin_b)
    mfma_xw<8><<<dim3(gemmG), blk, 0, stream>>>(x, linP, lin_b, h_bf, N);

    // ---- layer 1: aggh = gather(h_bf); GRU -> h_bf ----
    gather_agg_bf<<<dim3(ngridW), blk, 0, stream>>>(h_bf, off, ssrc, aggh, N);
    mfma_gru<1, 0><<<dim3(gruG), dim3(512), 0, stream>>>(aggh, h_bf, wc1P, whh1P, bih1, bhh1, nullptr, h_bf, N, NT);

    // ---- layer 2: aggh = gather(h_bf); GRU -> feats (f32) ----
    gather_agg_bf<<<dim3(ngridW), blk, 0, stream>>>(h_bf, off, ssrc, aggh, N);
    mfma_gru<0, 1><<<dim3(gruG), dim3(512), 0, stream>>>(aggh, h_bf, wc2P, whh2P, bih2, bhh2, feats, nullptr, N, NT);

    // ---- classifier + loss ----
    cls_kernel<<<dim3(ngridW), blk, 0, stream>>>(feats, cls_w, cls_b, y, logits, part, N, 1.0f / (float)N);
    loss_reduce<<<dim3(1), dim3(1024), 0, stream>>>(part, loss, P);
}

// Round 21
// 220.014 us; speedup vs baseline: 1.3925x; 1.0402x over previous
//
#include <hip/hip_runtime.h>
#include <cstddef>
#include <cstdint>

typedef __attribute__((ext_vector_type(8))) short bf16x8;
typedef __attribute__((ext_vector_type(4))) float f32x4;
typedef __attribute__((ext_vector_type(8))) unsigned short u16x8;

__device__ inline unsigned short f2bf(float f) {
    unsigned u = __builtin_bit_cast(unsigned, f);
    u += 0x7FFF + ((u >> 16) & 1);          // round-to-nearest-even
    return (unsigned short)(u >> 16);
}
__device__ inline float bfbits_lo(unsigned v) { return __builtin_bit_cast(float, v << 16); }
__device__ inline float bfbits_hi(unsigned v) { return __builtin_bit_cast(float, v & 0xffff0000u); }
__device__ inline float bf2f(unsigned short b) { return __builtin_bit_cast(float, (unsigned)b << 16); }

// fast device math (v_exp_f32 / v_rcp_f32 paths)
__device__ inline float fsigmoid(float x) { return 1.0f / (1.0f + __expf(-x)); }
__device__ inline float ftanh(float x)    { return 1.0f - 2.0f / (__expf(2.0f * x) + 1.0f); }

// XOR-swizzled byte offset into a [rows][32 bf16] LDS tile (64B rows).
__device__ inline int swzB(int row, int slot) {
    return row * 64 + ((slot ^ ((row >> 1) & 3)) << 4);
}
__device__ inline bf16x8 ldbf8(const unsigned short* p) {
    u16x8 v = *(const u16x8*)p;
    return __builtin_bit_cast(bf16x8, v);
}

// ---------------- fused weight prep (one dispatch, 896 blocks) ----------------
// blocks [0,128): prepack lin_w [256,128] -> linP
// blocks [128,512): wcomb w1/w2 @ wih1/wih2^T -> wc1P/wc2P (192 blocks each)
// blocks [512,896): prepack whh1/whh2 (trans) -> whh1P/whh2P (192 blocks each)
__global__ __launch_bounds__(256)
void weight_prep_kernel(const float* __restrict__ lin_w,
                        const float* __restrict__ w1, const float* __restrict__ wih1,
                        const float* __restrict__ w2, const float* __restrict__ wih2,
                        const float* __restrict__ whh1, const float* __restrict__ whh2,
                        unsigned short* __restrict__ linP,
                        unsigned short* __restrict__ wc1P, unsigned short* __restrict__ wc2P,
                        unsigned short* __restrict__ whh1P, unsigned short* __restrict__ whh2P)
{
    const int b = blockIdx.x;
    if (b < 128) {
        // prepack lin: P[kc][c][kk] = lin_w[k][c], K=256, C=128
        int idx = b * 256 + threadIdx.x;
        int kk = idx & 31;
        int c  = (idx >> 5) & 127;
        int kc = idx >> 12;
        int k  = kc * 32 + kk;
        linP[idx] = f2bf(lin_w[(size_t)k * 128 + c]);
    } else if (b < 512) {
        // combined weight: Wc[d][c] = sum_t Wm[d*128+t] * Wih[c*128+t]
        int bb = b - 128;
        const float* Wm  = (bb < 192) ? w1 : w2;
        const float* Wih = (bb < 192) ? wih1 : wih2;
        unsigned short* P = (bb < 192) ? wc1P : wc2P;
        int idx = (bb % 192) * 256 + threadIdx.x;     // 0..49151
        int kk = idx & 31;
        int c  = (idx >> 5) % 384;
        int kc = idx / (32 * 384);
        int d  = kc * 32 + kk;
        const float4* a = (const float4*)&Wm[(size_t)d * 128];
        const float4* bv4 = (const float4*)&Wih[(size_t)c * 128];
        float s = 0.0f;
#pragma unroll 8
        for (int t = 0; t < 32; ++t) {
            float4 av = a[t], bv = bv4[t];
            s += av.x * bv.x + av.y * bv.y + av.z * bv.z + av.w * bv.w;
        }
        P[idx] = f2bf(s);
    } else {
        // prepack whh (trans): P[kc][c][kk] = whh[c][k], K=128, C=384
        int bb = b - 512;
        const float* S = (bb < 192) ? whh1 : whh2;
        unsigned short* P = (bb < 192) ? whh1P : whh2P;
        int idx = (bb % 192) * 256 + threadIdx.x;
        int kk = idx & 31;
        int c  = (idx >> 5) % 384;
        int kc = idx / (32 * 384);
        int k  = kc * 32 + kk;
        P[idx] = f2bf(S[(size_t)c * 128 + k]);
    }
}

// ---------------- MFMA GEMM (input projection): h_bf = bf16(x@linW + b) ----------------
template<int KC>
__global__ __launch_bounds__(256)
void mfma_xw(const float* __restrict__ A, const unsigned short* __restrict__ P,
             const float* __restrict__ bias, unsigned short* __restrict__ Cbf, int M)
{
    __shared__ unsigned short Ab[KC * 2048];   // [kc][64 rows][32 k], swizzled per kc
    const int tid  = threadIdx.x;
    const int l    = tid & 63;
    const int w    = tid >> 6;
    const int wr   = w >> 1, wc = w & 1;
    const int row0 = blockIdx.x * 64;
    const int K    = KC * 32;

    {
        int row = tid >> 2, slot = tid & 3, kpos = slot * 8;
#pragma unroll
        for (int kc = 0; kc < KC; ++kc) {
            unsigned short u[8];
            if (row0 + row < M) {
                const float* src = &A[(size_t)(row0 + row) * K + kc * 32 + kpos];
                float4 v0 = *(const float4*)src;
                float4 v1 = *(const float4*)(src + 4);
                u[0]=f2bf(v0.x); u[1]=f2bf(v0.y); u[2]=f2bf(v0.z); u[3]=f2bf(v0.w);
                u[4]=f2bf(v1.x); u[5]=f2bf(v1.y); u[6]=f2bf(v1.z); u[7]=f2bf(v1.w);
            } else {
#pragma unroll
                for (int q = 0; q < 8; ++q) u[q] = 0;
            }
            *(u16x8*)((char*)Ab + kc * 4096 + swzB(row, slot)) = *(u16x8*)u;
        }
    }
    __syncthreads();

    f32x4 acc[2][4];
#pragma unroll
    for (int i = 0; i < 2; ++i)
#pragma unroll
        for (int j = 0; j < 4; ++j) acc[i][j] = (f32x4){0.f, 0.f, 0.f, 0.f};

#pragma unroll
    for (int kc = 0; kc < KC; ++kc) {
        bf16x8 af[2], bf[4];
#pragma unroll
        for (int rt = 0; rt < 2; ++rt)
            af[rt] = *(const bf16x8*)((const char*)Ab + kc * 4096 +
                                      swzB(wr * 32 + rt * 16 + (l & 15), l >> 4));
#pragma unroll
        for (int ct = 0; ct < 4; ++ct) {
            int c = wc * 64 + ct * 16 + (l & 15);
            bf[ct] = ldbf8(&P[(size_t)kc * 4096 + c * 32 + (l >> 4) * 8]);
        }
#pragma unroll
        for (int rt = 0; rt < 2; ++rt)
#pragma unroll
            for (int ct = 0; ct < 4; ++ct)
                acc[rt][ct] = __builtin_amdgcn_mfma_f32_16x16x32_bf16(af[rt], bf[ct], acc[rt][ct], 0, 0, 0);
    }

#pragma unroll
    for (int rt = 0; rt < 2; ++rt)
#pragma unroll
        for (int ct = 0; ct < 4; ++ct) {
            int col = wc * 64 + ct * 16 + (l & 15);
            float bv = bias ? bias[col] : 0.0f;
#pragma unroll
            for (int j = 0; j < 4; ++j) {
                int row = row0 + wr * 32 + rt * 16 + (l >> 4) * 4 + j;
                if (row < M) Cbf[(size_t)row * 128 + col] = f2bf(acc[rt][ct][j] + bv);
            }
        }
}

// ---------------- fused gi/gh GEMMs + GRU, B-in-registers, grid-stride tiles ----------------
template<int ELU, int OUTF32>
__global__ __launch_bounds__(512, 2)
void mfma_gru(const unsigned short* __restrict__ agghbf, const unsigned short* __restrict__ hbf,
              const unsigned short* __restrict__ wcP, const unsigned short* __restrict__ whhP,
              const float* __restrict__ bih, const float* __restrict__ bhh,
              float* __restrict__ hout, unsigned short* __restrict__ houtbf,
              int M, int ntiles)
{
    __shared__ unsigned short Aa[4096];   // [kc][32 rows][32 k] swizzled, 8KB
    __shared__ unsigned short Ah[4096];
    const int tid = threadIdx.x;
    const int l   = tid & 63;
    const int g   = tid >> 6;             // wave = unit group

    const int skc = tid >> 7;             // staging kc
    const int t3  = tid & 127;
    const int srow = t3 >> 2, sslot = t3 & 3, skpos = sslot * 8;
    const int slbyte = skc * 2048 + swzB(srow, sslot);

    const int unit = g * 16 + (l & 15);
    const int kcu = unit >> 5, slotu = (unit & 31) >> 3, elemu = unit & 7;
    const float bir = bih[unit], biz = bih[128 + unit], bin = bih[256 + unit];
    const float bhr = bhh[unit], bhz = bhh[128 + unit], bhn = bhh[256 + unit];

    // B fragments in registers (block-invariant): 24 x bf16x8 = 96 VGPR
    bf16x8 BW[4][3], BU[4][3];
#pragma unroll
    for (int kc = 0; kc < 4; ++kc)
#pragma unroll
        for (int gr = 0; gr < 3; ++gr) {
            int c = gr * 128 + g * 16 + (l & 15);
            size_t boff = (size_t)kc * 12288 + c * 32 + (l >> 4) * 8;
            BW[kc][gr] = ldbf8(&wcP[boff]);
            BU[kc][gr] = ldbf8(&whhP[boff]);
        }

    u16x8 ua = (u16x8){0,0,0,0,0,0,0,0};
    u16x8 uh = (u16x8){0,0,0,0,0,0,0,0};
    {
        int row0 = blockIdx.x * 32;
        if (row0 + srow < M && row0 < ntiles * 32) {
            size_t goff = (size_t)(row0 + srow) * 128 + skc * 32 + skpos;
            ua = *(const u16x8*)&agghbf[goff];
            uh = *(const u16x8*)&hbf[goff];
        }
    }

    for (int t = blockIdx.x; t < ntiles; t += gridDim.x) {
        const int row0 = t * 32;
        __syncthreads();
        *(u16x8*)((char*)Aa + slbyte) = ua;
        *(u16x8*)((char*)Ah + slbyte) = uh;
        __syncthreads();

        {
            int tn = t + gridDim.x;
            ua = (u16x8){0,0,0,0,0,0,0,0};
            uh = (u16x8){0,0,0,0,0,0,0,0};
            if (tn < ntiles) {
                int r0n = tn * 32;
                if (r0n + srow < M) {
                    size_t goff = (size_t)(r0n + srow) * 128 + skc * 32 + skpos;
                    ua = *(const u16x8*)&agghbf[goff];
                    uh = *(const u16x8*)&hbf[goff];
                }
            }
        }

        f32x4 gi[3][2], gh[3][2];
#pragma unroll
        for (int gr = 0; gr < 3; ++gr)
#pragma unroll
            for (int rt = 0; rt < 2; ++rt) {
                gi[gr][rt] = (f32x4){0.f, 0.f, 0.f, 0.f};
                gh[gr][rt] = (f32x4){0.f, 0.f, 0.f, 0.f};
            }

#pragma unroll
        for (int kc = 0; kc < 4; ++kc) {
            bf16x8 aa[2], ah[2];
#pragma unroll
            for (int rt = 0; rt < 2; ++rt) {
                int lbyte = kc * 2048 + swzB(rt * 16 + (l & 15), l >> 4);
                aa[rt] = *(const bf16x8*)((const char*)Aa + lbyte);
                ah[rt] = *(const bf16x8*)((const char*)Ah + lbyte);
            }
#pragma unroll
            for (int gr = 0; gr < 3; ++gr)
#pragma unroll
                for (int rt = 0; rt < 2; ++rt) {
                    gi[gr][rt] = __builtin_amdgcn_mfma_f32_16x16x32_bf16(aa[rt], BW[kc][gr], gi[gr][rt], 0, 0, 0);
                    gh[gr][rt] = __builtin_amdgcn_mfma_f32_16x16x32_bf16(ah[rt], BU[kc][gr], gh[gr][rt], 0, 0, 0);
                }
        }

#pragma unroll
        for (int rt = 0; rt < 2; ++rt)
#pragma unroll
            for (int j = 0; j < 4; ++j) {
                int rl = rt * 16 + (l >> 4) * 4 + j;
                int row = row0 + rl;
                if (row >= M) continue;
                float hv = bf2f(*(const unsigned short*)
                                ((const char*)Ah + kcu * 2048 + swzB(rl, slotu) + elemu * 2));
                float rr = fsigmoid(gi[0][rt][j] + bir + gh[0][rt][j] + bhr);
                float z  = fsigmoid(gi[1][rt][j] + biz + gh[1][rt][j] + bhz);
                float nn = ftanh(gi[2][rt][j] + bin + rr * (gh[2][rt][j] + bhn));
                float o  = (1.0f - z) * nn + z * hv;
                if (ELU) o = (o > 0.0f) ? o : (__expf(o) - 1.0f);
                if (OUTF32) hout[(size_t)row * 128 + unit] = o;
                else        houtbf[(size_t)row * 128 + unit] = f2bf(o);
            }
    }
}

// ---------------- atomic-free two-level bucketed CSR build ----------------
// bucket = dst >> 8 ; chunk = 4096 edges. bh[chunk][256] histogram matrix.

#define CHUNK 4096

__global__ __launch_bounds__(1024)
void chunk_hist_kernel(const int* __restrict__ dst, int* __restrict__ bh, int E)
{
    __shared__ int lh[256];
    const int c = blockIdx.x, tid = threadIdx.x;
    if (tid < 256) lh[tid] = 0;
    __syncthreads();
#pragma unroll
    for (int q = 0; q < 4; ++q) {
        int e = c * CHUNK + q * 1024 + tid;
        if (e < E) atomicAdd(&lh[dst[e] >> 8], 1);
    }
    __syncthreads();
    if (tid < 256) bh[c * 256 + tid] = lh[tid];
}

__global__ __launch_bounds__(256)
void colscan_kernel(int* __restrict__ bh, int* __restrict__ bcnt, int NCH)
{
    __shared__ int wt[4];
    __shared__ int carry;
    const int b = blockIdx.x;
    const int tid = threadIdx.x, lane = tid & 63, w4 = tid >> 6;
    if (tid == 0) carry = 0;
    __syncthreads();
    for (int base = 0; base < NCH; base += 256) {
        int c = base + tid;
        int v = (c < NCH) ? bh[c * 256 + b] : 0;
        int s = v;
#pragma unroll
        for (int o = 1; o < 64; o <<= 1) {
            int n = __shfl_up(s, o, 64);
            if (lane >= o) s += n;
        }
        if (lane == 63) wt[w4] = s;
        __syncthreads();
        int wpre = 0;
        for (int q = 0; q < w4; ++q) wpre += wt[q];
        int ex = carry + wpre + s - v;
        if (c < NCH) bh[c * 256 + b] = ex;
        __syncthreads();
        if (tid == 255) carry = ex + v;
        __syncthreads();
    }
    if (tid == 0) bcnt[b] = carry;
}

__global__ __launch_bounds__(256)
void bscan2_kernel(const int* __restrict__ bcnt, int* __restrict__ bbase,
                   int* __restrict__ off, int N, int E)
{
    __shared__ int wt[4];
    const int tid = threadIdx.x, lane = tid & 63, w4 = tid >> 6;
    int v = bcnt[tid];
    int s = v;
#pragma unroll
    for (int o = 1; o < 64; o <<= 1) {
        int n = __shfl_up(s, o, 64);
        if (lane >= o) s += n;
    }
    if (lane == 63) wt[w4] = s;
    __syncthreads();
    int wpre = 0;
    for (int q = 0; q < w4; ++q) wpre += wt[q];
    bbase[tid] = wpre + s - v;
    if (tid == 0) off[N] = E;
}

__global__ __launch_bounds__(1024)
void place_kernel(const int* __restrict__ src, const int* __restrict__ dst,
                  const int* __restrict__ bh, const int* __restrict__ bbase,
                  unsigned long long* __restrict__ bpair, int E)
{
    __shared__ int cur[256];
    const int c = blockIdx.x, tid = threadIdx.x;
    if (tid < 256) cur[tid] = bbase[tid] + bh[c * 256 + tid];
    __syncthreads();
#pragma unroll
    for (int q = 0; q < 4; ++q) {
        int e = c * CHUNK + q * 1024 + tid;
        if (e < E) {
            int d = dst[e];
            int pos = atomicAdd(&cur[d >> 8], 1);
            bpair[(size_t)pos] = ((unsigned long long)(unsigned)d << 32) | (unsigned)src[e];
        }
    }
}

__global__ __launch_bounds__(1024)
void bucket_sort_kernel(const unsigned long long* __restrict__ bpair,
                        const int* __restrict__ bcnt, const int* __restrict__ bbase,
                        int* __restrict__ off, int* __restrict__ ssrc, int N)
{
    __shared__ int hist[256];
    __shared__ int wt[4];
    const int b = blockIdx.x;
    const int tid = threadIdx.x;
    const int cnt = bcnt[b];
    const int base = bbase[b];

    if (tid < 256) hist[tid] = 0;
    __syncthreads();
    for (int i = tid; i < cnt; i += 1024) {
        unsigned long long p = bpair[(size_t)base + i];
        atomicAdd(&hist[(int)(p >> 32) & 255], 1);
    }
    __syncthreads();

    int ex = 0;
    {
        int lane = tid & 63, w4 = tid >> 6;
        int v = (tid < 256) ? hist[tid] : 0;
        int s = v;
#pragma unroll
        for (int o = 1; o < 64; o <<= 1) {
            int n = __shfl_up(s, o, 64);
            if (lane >= o) s += n;
        }
        if (tid < 256 && lane == 63) wt[w4] = s;
        __syncthreads();
        if (tid < 256) {
            int wpre = 0;
            for (int q = 0; q < w4; ++q) wpre += wt[q];
            ex = wpre + s - v;
        }
    }
    __syncthreads();
    if (tid < 256) {
        int d = (b << 8) + tid;
        if (d < N) off[d] = base + ex;
        hist[tid] = ex;            // reuse as cursor
    }
    __syncthreads();
    for (int i = tid; i < cnt; i += 1024) {
        unsigned long long p = bpair[(size_t)base + i];
        int d = (int)(p >> 32) & 255;
        int pos = atomicAdd(&hist[d], 1);
        ssrc[(size_t)base + pos] = (int)(unsigned)p;
    }
}

// one wave per dst node, bf16 rows: aggh[n] = sum of hbf[ssrc[e]] rows.
__global__ __launch_bounds__(256)
void gather_agg_bf(const unsigned short* __restrict__ m, const int* __restrict__ off,
                   const int* __restrict__ ssrc, unsigned short* __restrict__ agg, int N)
{
    int w = (blockIdx.x * 256 + threadIdx.x) >> 6;
    int lane = threadIdx.x & 63;
    if (w >= N) return;
    int half = lane >> 5, hl = lane & 31;
    int e0 = off[w], e1 = off[w + 1];
    float a0[4] = {0.f, 0.f, 0.f, 0.f};
    float a1[4] = {0.f, 0.f, 0.f, 0.f};
    int e = e0 + half;
    for (; e + 2 < e1; e += 4) {
        int s0 = ssrc[e], s1 = ssrc[e + 2];
        uint2 v0 = *(const uint2*)&m[(size_t)s0 * 128 + hl * 4];
        uint2 v1 = *(const uint2*)&m[(size_t)s1 * 128 + hl * 4];
        a0[0] += bfbits_lo(v0.x); a0[1] += bfbits_hi(v0.x);
        a0[2] += bfbits_lo(v0.y); a0[3] += bfbits_hi(v0.y);
        a1[0] += bfbits_lo(v1.x); a1[1] += bfbits_hi(v1.x);
        a1[2] += bfbits_lo(v1.y); a1[3] += bfbits_hi(v1.y);
    }
    if (e < e1) {
        int s0 = ssrc[e];
        uint2 v0 = *(const uint2*)&m[(size_t)s0 * 128 + hl * 4];
        a0[0] += bfbits_lo(v0.x); a0[1] += bfbits_hi(v0.x);
        a0[2] += bfbits_lo(v0.y); a0[3] += bfbits_hi(v0.y);
    }
    float o[4];
#pragma unroll
    for (int j = 0; j < 4; ++j) o[j] = a0[j] + a1[j];
#pragma unroll
    for (int j = 0; j < 4; ++j) o[j] += __shfl_xor(o[j], 32, 64);
    if (half == 0) {
        uint2 pk;
        pk.x = (unsigned)f2bf(o[0]) | ((unsigned)f2bf(o[1]) << 16);
        pk.y = (unsigned)f2bf(o[2]) | ((unsigned)f2bf(o[3]) << 16);
        *(uint2*)&agg[(size_t)w * 128 + hl * 4] = pk;
    }
}

// one wave per node: logits = h@W + b ; log_softmax ; per-block partial loss
__global__ __launch_bounds__(256)
void cls_kernel(const float* __restrict__ h, const float* __restrict__ W,
                const float* __restrict__ b, const int* __restrict__ y,
                float* __restrict__ logitsOut, float* __restrict__ partials,
                int N, float invN)
{
    __shared__ float pl[4];
    const int wid  = threadIdx.x >> 6;
    const int lane = threadIdx.x & 63;
    const int gw   = blockIdx.x * 4 + wid;
    if (threadIdx.x < 4) pl[threadIdx.x] = 0.0f;
    __syncthreads();
    if (gw < N) {
        float h0 = h[(size_t)gw * 128 + lane * 2];
        float h1 = h[(size_t)gw * 128 + lane * 2 + 1];
        float acc[6];
#pragma unroll
        for (int c = 0; c < 6; ++c)
            acc[c] = h0 * W[(lane * 2) * 6 + c] + h1 * W[(lane * 2 + 1) * 6 + c];
#pragma unroll
        for (int off = 32; off >= 1; off >>= 1)
#pragma unroll
            for (int c = 0; c < 6; ++c)
                acc[c] += __shfl_xor(acc[c], off, 64);
        float logit[6];
#pragma unroll
        for (int c = 0; c < 6; ++c) logit[c] = acc[c] + b[c];
#pragma unroll
        for (int c = 0; c < 6; ++c)
            if (lane == c) logitsOut[(size_t)gw * 6 + c] = logit[c];
        if (lane == 0) {
            float mx = logit[0];
#pragma unroll
            for (int c = 1; c < 6; ++c) mx = fmaxf(mx, logit[c]);
            float se = 0.0f;
#pragma unroll
            for (int c = 0; c < 6; ++c) se += expf(logit[c] - mx);
            float lse = mx + logf(se);
            int yy = y[gw];
            float ly = 0.0f;
#pragma unroll
            for (int c = 0; c < 6; ++c)
                if (yy == c) ly = logit[c];
            pl[wid] = (lse - ly) * invN;
        }
    }
    __syncthreads();
    if (threadIdx.x == 0)
        partials[blockIdx.x] = pl[0] + pl[1] + pl[2] + pl[3];
}

__global__ __launch_bounds__(1024)
void loss_reduce(const float* __restrict__ partials, float* __restrict__ loss, int P)
{
    __shared__ float buf[1024];
    float s = 0.0f;
    for (int i = threadIdx.x; i < (unsigned)P; i += 1024) s += partials[i];
    buf[threadIdx.x] = s;
    __syncthreads();
    for (int o = 512; o >= 1; o >>= 1) {
        if (threadIdx.x < (unsigned)o) buf[threadIdx.x] += buf[threadIdx.x + o];
        __syncthreads();
    }
    if (threadIdx.x == 0) loss[0] = buf[0];
}

extern "C" void kernel_launch(void* const* d_in, const int* in_sizes, int n_in,
                              void* d_out, int out_size, void* d_ws, size_t ws_size,
                              hipStream_t stream)
{
    const float* x     = (const float*)d_in[0];
    const int*   eidx  = (const int*)d_in[1];
    const int*   y     = (const int*)d_in[2];
    const float* lin_w = (const float*)d_in[3];
    const float* lin_b = (const float*)d_in[4];
    const float* w1    = (const float*)d_in[5];
    const float* wih1  = (const float*)d_in[6];
    const float* whh1  = (const float*)d_in[7];
    const float* bih1  = (const float*)d_in[8];
    const float* bhh1  = (const float*)d_in[9];
    const float* w2    = (const float*)d_in[10];
    const float* wih2  = (const float*)d_in[11];
    const float* whh2  = (const float*)d_in[12];
    const float* bih2  = (const float*)d_in[13];
    const float* bhh2  = (const float*)d_in[14];
    const float* cls_w = (const float*)d_in[15];
    const float* cls_b = (const float*)d_in[16];

    const int N   = in_sizes[2];
    const int E   = in_sizes[1] / 2;
    const int L   = 6;
    const size_t NH = (size_t)N * 128;
    const int P   = (N + 3) / 4;
    const int NT  = (N + 31) / 32;       // gru row tiles
    const int NCH = (E + CHUNK - 1) / CHUNK;
    const int NBK = (N + 255) >> 8;

    float* out    = (float*)d_out;
    float* logits = out;
    float* loss   = out + (size_t)N * L;
    float* feats  = out + (size_t)N * L + 1;

    float* ws   = (float*)d_ws;
    float* part = ws;                 // P f32

    unsigned short* h_bf   = (unsigned short*)(part + P);  // NH bf16
    unsigned short* aggh   = h_bf + NH;                    // NH bf16
    unsigned short* linP   = aggh + NH;                    // 256*128
    unsigned short* wc1P   = linP  + 32768;                // [4][384][32]
    unsigned short* whh1P  = wc1P  + 49152;
    unsigned short* wc2P   = whh1P + 49152;
    unsigned short* whh2P  = wc2P  + 49152;

    int* off   = (int*)(whh2P + 49152);    // N+1 (+1 pad)
    int* bcnt  = off + (N + 2);            // 256
    int* bbase = bcnt + 256;               // 256
    int* bh    = bbase + 256;              // NCH*256
    unsigned long long* bpair =
        (unsigned long long*)(((uintptr_t)(bh + (size_t)NCH * 256) + 7) & ~(uintptr_t)7);  // E
    int* ssrc  = (int*)(bpair + E);        // E

    const int* src = eidx;
    const int* dst = eidx + E;

    dim3 blk(256);
    unsigned ngridW = (unsigned)((N + 3) / 4);
    unsigned gemmG  = (unsigned)((N + 63) / 64);
    unsigned gruG   = (unsigned)(NT < 256 ? NT : 256);

    // ---- atomic-free bucketed CSR build (once; reused by both layers) ----
    chunk_hist_kernel<<<dim3((unsigned)NCH), dim3(1024), 0, stream>>>(dst, bh, E);
    colscan_kernel<<<dim3(256), dim3(256), 0, stream>>>(bh, bcnt, NCH);
    bscan2_kernel<<<dim3(1), dim3(256), 0, stream>>>(bcnt, bbase, off, N, E);
    place_kernel<<<dim3((unsigned)NCH), dim3(1024), 0, stream>>>(src, dst, bh, bbase, bpair, E);
    bucket_sort_kernel<<<dim3((unsigned)NBK), dim3(1024), 0, stream>>>(bpair, bcnt, bbase, off, ssrc, N);

    // ---- fused weight prep (single dispatch) ----
    weight_prep_kernel<<<dim3(896), blk, 0, stream>>>(lin_w, w1, wih1, w2, wih2, whh1, whh2,
                                                      linP, wc1P, wc2P, whh1P, whh2P);

    // h_bf = bf16(x @ lin_w + lin_b)
    mfma_xw<8><<<dim3(gemmG), blk, 0, stream>>>(x, linP, lin_b, h_bf, N);

    // ---- layer 1: aggh = gather(h_bf); GRU -> h_bf ----
    gather_agg_bf<<<dim3(ngridW), blk, 0, stream>>>(h_bf, off, ssrc, aggh, N);
    mfma_gru<1, 0><<<dim3(gruG), dim3(512), 0, stream>>>(aggh, h_bf, wc1P, whh1P, bih1, bhh1, nullptr, h_bf, N, NT);

    // ---- layer 2: aggh = gather(h_bf); GRU -> feats (f32) ----
    gather_agg_bf<<<dim3(ngridW), blk, 0, stream>>>(h_bf, off, ssrc, aggh, N);
    mfma_gru<0, 1><<<dim3(gruG), dim3(512), 0, stream>>>(aggh, h_bf, wc2P, whh2P, bih2, bhh2, feats, nullptr, N, NT);

    // ---- classifier + loss ----
    cls_kernel<<<dim3(ngridW), blk, 0, stream>>>(feats, cls_w, cls_b, y, logits, part, N, 1.0f / (float)N);
    loss_reduce<<<dim3(1), dim3(1024), 0, stream>>>(part, loss, P);
}